// Round 12
// baseline (308.986 us; speedup 1.0000x reference)
//
#include <hip/hip_runtime.h>
#include <hip/hip_fp16.h>
#include <cstdint>
#include <cstddef>

// ---------------------------------------------------------------------------
// TopoGNN: 3x SAGEConv(mean) + BN + ReLU, softmax-attention pooling, 2 heads.
// N=100000 nodes, E=1600000 edges, B=64 segments, IN_CH=6, HID=64.
// R5 (754us) bucket-CSR. R12 (474us) MFMA GEMM. R17/R19 (381us) fp8 gather.
// R20 (373us) agg fused into MFMA. R21 (361us) merges. R22 (357us) h fp16.
// R23 (766us REGR): per-block __threadfence evicts L2. Never fence gathers.
// R24 (341us): fence-free merges. R25 (357us REGR): stats broadcast folds.
// R26 (339us): h16-elim. R27 (329us): BN-on-the-fly, raw h fp8.
// R28 (322.8us): stats1 in csr_sage1. R29 (300.8us): transpose-read stats1.
// R30 (325.1us REGR): 8-wide IN-LANE gather unroll — longer dependent VALU
//     chains at low occupancy. LESSON: don't deepen per-lane chains.
// R31 (299.9us): revert to R29. Anchor confirmed.
// R32: gather MLP via NODE-parallelism: 8 groups x 8 lanes (was 4 x 16).
//     Each lane loads uint2 (8ch); wave holds 8 nodes in flight (32 reqs,
//     was 16) with UNCHANGED 4-deep slot chains (same j%4 partition ->
//     numerically identical). Wave serial edge-steps 4*max4(deg) ->
//     2*max8(deg) (~88->~48). No cross-lane combine; 16B LDS store.
// ---------------------------------------------------------------------------

#define EPB 8192   // edges per partition block (256 thr x 32)
#define NBIN 512   // padded bucket count (actual NB = ceil(N/256) <= 512)
#define EPS_BN 1e-5f

typedef _Float16 f16x8 __attribute__((ext_vector_type(8)));
typedef float    f32x4 __attribute__((ext_vector_type(4)));
typedef float    f32x2 __attribute__((ext_vector_type(2)));

// ---- merged: per-block bucket histogram (bid < nBlk) + prep roles --------
__global__ __launch_bounds__(256) void prep_hist(
    const int* __restrict__ dst, int* __restrict__ blockBin,
    int* __restrict__ binTotal, int E, int nBlk,
    const float* __restrict__ x, float* __restrict__ sumexp, int n,
    const int* __restrict__ batch, int* __restrict__ lb,
    const float* __restrict__ W2l, const float* __restrict__ W2r,
    const float* __restrict__ W3l, const float* __restrict__ W3r,
    __half* __restrict__ wfrag2, __half* __restrict__ wfrag3)
{
    __shared__ int hist[NBIN];
    __shared__ float wsum[4];
    int t = threadIdx.x;
    int bid = blockIdx.x;
    if (bid < nBlk) {
        for (int i = t; i < NBIN; i += 256) hist[i] = 0;
        __syncthreads();
        int e0 = bid * EPB;
#pragma unroll
        for (int k = 0; k < 32; k++) {
            int e = e0 + (k << 8) + t;
            if (e < E) atomicAdd(&hist[dst[e] >> 8], 1);
        }
        __syncthreads();
        for (int i = t; i < NBIN; i += 256) {
            int c = hist[i];
            blockBin[bid * NBIN + i] = c;
            if (c) atomicAdd(&binTotal[i], c);
        }
        return;
    }
    int pbid = bid - nBlk;
    if (pbid < 256) {
        float s = 0.f;
        int stride = 256 * 256;
        for (int i = pbid * 256 + t; i < n; i += stride)
            s += expf(x[(size_t)i * 6 + 4]);
#pragma unroll
        for (int o = 32; o > 0; o >>= 1) s += __shfl_down(s, o, 64);
        if ((t & 63) == 0) wsum[t >> 6] = s;
        __syncthreads();
        if (t == 0)
            unsafeAtomicAdd(sumexp, wsum[0] + wsum[1] + wsum[2] + wsum[3]);
    } else if (pbid == 256) {
        int b = t;
        if (b > 64) return;
        int lo = 0, hi = n;
        while (lo < hi) {
            int mid = (lo + hi) >> 1;
            if (batch[mid] < b) lo = mid + 1; else hi = mid;
        }
        lb[b] = lo;
    } else {
        bool second = (pbid >= 289);
        int i = (pbid - (second ? 289 : 257)) * 256 + t;
        if (i >= 8192) return;
        int j    = i & 7;
        int m    = (i >> 3) & 15;
        int quad = (i >> 7) & 3;
        int tt   = (i >> 9) & 3;
        int q    = i >> 11;
        int k    = (q & 1) * 32 + quad * 8 + j;
        int col  = tt * 16 + m;
        const float* W = second ? ((q < 2) ? W3l : W3r)
                                : ((q < 2) ? W2l : W2r);
        (second ? wfrag3 : wfrag2)[i] = __float2half_rn(W[k * 64 + col]);
    }
}

// ---- phase B: scan of bin totals + per-bin exclusive block-count scan ----
__global__ __launch_bounds__(512) void blockbin_offs(int* __restrict__ blockBin,
                                                     const int* __restrict__ binTotal,
                                                     int* __restrict__ binBase,
                                                     int* __restrict__ rowptrN,
                                                     int nBlk)
{
    __shared__ int s[NBIN];
    int t = threadIdx.x;
    int tot = binTotal[t];
    s[t] = tot;
    __syncthreads();
    for (int off = 1; off < NBIN; off <<= 1) {
        int v = (t >= off) ? s[t - off] : 0;
        __syncthreads();
        s[t] += v;
        __syncthreads();
    }
    int excl = s[t] - tot;
    if (blockIdx.x == 0) {
        binBase[t] = excl;
        if (t == NBIN - 1) { binBase[NBIN] = s[t]; *rowptrN = s[t]; }
    }
    __syncthreads();

    int wv   = t >> 6;              // 0..7
    int lane = t & 63;
    int bin  = blockIdx.x * 8 + wv;
    int carry = s[bin] - binTotal[bin];   // exclusive base for this bin
    for (int c0 = 0; c0 < nBlk; c0 += 64) {
        int blk = c0 + lane;
        int cnt = (blk < nBlk) ? blockBin[blk * NBIN + bin] : 0;
        int v = cnt;
#pragma unroll
        for (int d = 1; d < 64; d <<= 1) {
            int u = __shfl_up(v, d, 64);
            if (lane >= d) v += u;
        }
        if (blk < nBlk) blockBin[blk * NBIN + bin] = carry + v - cnt;
        carry += __shfl(v, 63, 64);
    }
}

// ---- phase C: place packed (src | local_dst<<24); per-block LDS cursors ---
__global__ __launch_bounds__(256) void bucket_scatter(const int* __restrict__ src,
                                                      const int* __restrict__ dst,
                                                      const int* __restrict__ blockBin,
                                                      int* __restrict__ epck, int E)
{
    __shared__ int cur[NBIN];
    int t = threadIdx.x;
    for (int i = t; i < NBIN; i += 256) cur[i] = blockBin[blockIdx.x * NBIN + i];
    __syncthreads();
    int e0 = blockIdx.x * EPB;
#pragma unroll
    for (int k = 0; k < 32; k++) {
        int e = e0 + (k << 8) + t;
        if (e < E) {
            int d = dst[e];
            int pos = atomicAdd(&cur[d >> 8], 1);
            epck[pos] = src[e] | ((d & 255) << 24);   // src < 2^24
        }
    }
}

// ---- merged phase D + layer 1 + layer-1 BN stats (transpose-read) --------
__global__ __launch_bounds__(256) void csr_sage1(
    const int* __restrict__ epck, const int* __restrict__ binBase,
    int* __restrict__ rowptr, int* __restrict__ eidx,
    const float* __restrict__ x,
    const float* __restrict__ Wl, const float* __restrict__ bias,
    const float* __restrict__ Wr, unsigned* __restrict__ out,
    float* __restrict__ statsTmp, int N)
{
    __shared__ int cnt[256], s[256], cur[256];
    __shared__ float4 sWl[6 * 16];
    __shared__ float4 sWr[6 * 16];
    __shared__ float ls[64], lss[64];
    __shared__ unsigned spx[256 * 16];   // 16KB: fp8 rows for stats transpose
    int t = threadIdx.x, bkt = blockIdx.x;
    for (int i = t; i < 6 * 16; i += 256) {
        sWl[i] = ((const float4*)Wl)[i];
        sWr[i] = ((const float4*)Wr)[i];
    }
    if (t < 64) { ls[t] = 0.f; lss[t] = 0.f; }
    int base = binBase[bkt], nE = binBase[bkt + 1] - base;
    cnt[t] = 0;
    __syncthreads();
    for (int j = t; j < nE; j += 256)
        atomicAdd(&cnt[(unsigned)epck[base + j] >> 24], 1);
    __syncthreads();
    s[t] = cnt[t];
    __syncthreads();
    for (int off = 1; off < 256; off <<= 1) {
        int v = (t >= off) ? s[t - off] : 0;
        __syncthreads();
        s[t] += v;
        __syncthreads();
    }
    int excl = s[t] - cnt[t];
    cur[t] = excl;
    int node = (bkt << 8) + t;
    bool valid = node < N;
    if (valid) rowptr[node] = base + excl;
    __syncthreads();
    for (int j = t; j < nE; j += 256) {
        int v = epck[base + j];
        int pos = atomicAdd(&cur[(unsigned)v >> 24], 1);
        eidx[base + pos] = v & 0xFFFFFF;     // contiguous 16KB span: stays in L2
    }
    __syncthreads();    // eidx writes drained to L2 before re-read; ls/lss init

    // ---- sage1 part: this block's nodes == this bucket (no early return) --
    int eb = base + excl, ee = base + s[t];   // empty for invalid nodes
    float a[6] = {0.f, 0.f, 0.f, 0.f, 0.f, 0.f};
    for (int j = eb; j < ee; j++) {
        int si = eidx[j];
        const float2* r = (const float2*)(x + (size_t)si * 6);
        float2 r0 = r[0], r1 = r[1], r2 = r[2];
        a[0] += r0.x; a[1] += r0.y; a[2] += r1.x;
        a[3] += r1.y; a[4] += r2.x; a[5] += r2.y;
    }
    float invd = 1.0f / fmaxf((float)(ee - eb), 1.0f);

    int nodeX = valid ? node : 0;             // OOB-safe x read
    const float2* xr2 = (const float2*)(x + (size_t)nodeX * 6);
    float2 x0 = xr2[0], x1 = xr2[1], x2 = xr2[2];
    float hh[6] = {x0.x, x0.y, x1.x, x1.y, x2.x, x2.y};

    float4 acc[16];
#pragma unroll
    for (int cg = 0; cg < 16; cg++) acc[cg] = ((const float4*)bias)[cg];
#pragma unroll
    for (int k = 0; k < 6; k++) {
        float am = a[k] * invd;
        float hk = hh[k];
#pragma unroll
        for (int cg = 0; cg < 16; cg++) {
            float4 wl = sWl[k * 16 + cg];
            float4 wr = sWr[k * 16 + cg];
            acc[cg].x = fmaf(am, wl.x, fmaf(hk, wr.x, acc[cg].x));
            acc[cg].y = fmaf(am, wl.y, fmaf(hk, wr.y, acc[cg].y));
            acc[cg].z = fmaf(am, wl.z, fmaf(hk, wr.z, acc[cg].z));
            acc[cg].w = fmaf(am, wl.w, fmaf(hk, wr.w, acc[cg].w));
        }
    }
    unsigned px[16];
#pragma unroll
    for (int cg = 0; cg < 16; cg++) {
        float4 av = acc[cg];
        int p = __builtin_amdgcn_cvt_pk_fp8_f32(av.x, av.y, 0, false);
        p     = __builtin_amdgcn_cvt_pk_fp8_f32(av.z, av.w, p, true);
        px[cg] = valid ? (unsigned)p : 0u;    // fp8 0x00 == +0.0 for stats
    }
    if (valid) {
        uint4* orow = (uint4*)(out + (size_t)node * 16);
        orow[0] = make_uint4(px[0],  px[1],  px[2],  px[3]);
        orow[1] = make_uint4(px[4],  px[5],  px[6],  px[7]);
        orow[2] = make_uint4(px[8],  px[9],  px[10], px[11]);
        orow[3] = make_uint4(px[12], px[13], px[14], px[15]);
    }
    // stage rows in LDS for the stats transpose
    {
        unsigned* row = &spx[t * 16];
#pragma unroll
        for (int cg = 0; cg < 16; cg++) row[cg] = px[cg];
    }
    __syncthreads();

    // ---- stats1 transpose-read: thread t = channel (t&63) x node-group ----
    {
        int c = t & 63, grp = t >> 6;
        int d = c >> 2, sh = (c & 3) * 8;
        float sv = 0.f, ssv = 0.f;
        const unsigned* col = &spx[(grp * 64) * 16 + d];
#pragma unroll 8
        for (int i = 0; i < 64; i++) {
            unsigned dw = col[i * 16];
            f32x2 p = __builtin_amdgcn_cvt_pk_f32_fp8(dw >> sh, false);
            float v = p[0];
            sv += v;
            ssv = fmaf(v, v, ssv);
        }
        atomicAdd(&ls[c], sv);
        atomicAdd(&lss[c], ssv);
    }
    __syncthreads();
    if (t < 64) {
        float* slot = statsTmp + (size_t)(bkt & 63) * 128;
        unsafeAtomicAdd(&slot[t], ls[t]);
        unsafeAtomicAdd(&slot[64 + t], lss[t]);
    }
}

// ---- fused BN-on-the-fly aggregation + MFMA GEMM + BN stats --------------
//      R32: gather = 8 groups x 8 lanes/wave; lane loads uint2 (8 ch).
#define TSTRIDE 72
__global__ __launch_bounds__(256) void agg_mm_mfma(
    const int* __restrict__ rowptr, const int* __restrict__ eidx,
    const unsigned* __restrict__ hr_in,
    const float* __restrict__ stats, const float* __restrict__ g,
    const float* __restrict__ be,
    const __half* __restrict__ wfh, const float* __restrict__ bias,
    unsigned char* __restrict__ hr_out, float* __restrict__ statsTmp,
    float invN, int n)
{
    __shared__ float ls[64], lss[64];
    __shared__ float ssc[64], ssh[64];
    __shared__ _Float16 sT[4][16 * TSTRIDE];   // 4 waves x 16 nodes x 64ch
    int t = threadIdx.x;
    if (t < 64) {
        ls[t] = 0.f; lss[t] = 0.f;
        float mu  = stats[t] * invN;
        float var = stats[64 + t] * invN - mu * mu;
        float sc  = g[t] / sqrtf(var + EPS_BN);
        ssc[t] = sc;
        ssh[t] = fmaf(-mu, sc, be[t]);
    }
    __syncthreads();   // ssc/ssh visible to all waves

    int wv = t >> 6, lane = t & 63;
    int node0 = (blockIdx.x * 4 + wv) * 16;

    // ---- gather phase: 8 groups x 8 lanes; lane owns channels 8*l8..+7 ----
    int grp = lane >> 3, l8 = lane & 7;
    float scv[8], shv[8];
#pragma unroll
    for (int k = 0; k < 8; k++) {
        scv[k] = ssc[8 * l8 + k];
        shv[k] = ssh[8 * l8 + k];
    }
#pragma unroll 1
    for (int r = 0; r < 2; r++) {
        int node = node0 + r * 8 + grp;
        int b = 0, e = 0;
        if (node < n) { b = rowptr[node]; e = rowptr[node + 1]; }

        float4 a0l = {0,0,0,0}, a0h = {0,0,0,0};
        float4 a1l = {0,0,0,0}, a1h = {0,0,0,0};
        float4 a2l = {0,0,0,0}, a2h = {0,0,0,0};
        float4 a3l = {0,0,0,0}, a3h = {0,0,0,0};
#define EDGE(S, AL, AH)                                                         \
        {                                                                       \
            uint2 rw = ((const uint2*)(hr_in + (size_t)(S) * 16))[l8];          \
            f32x2 q0 = __builtin_amdgcn_cvt_pk_f32_fp8(rw.x, false);            \
            f32x2 q1 = __builtin_amdgcn_cvt_pk_f32_fp8(rw.x, true);             \
            f32x2 q2 = __builtin_amdgcn_cvt_pk_f32_fp8(rw.y, false);            \
            f32x2 q3 = __builtin_amdgcn_cvt_pk_f32_fp8(rw.y, true);             \
            AL.x += fmaxf(fmaf(q0[0], scv[0], shv[0]), 0.f);                    \
            AL.y += fmaxf(fmaf(q0[1], scv[1], shv[1]), 0.f);                    \
            AL.z += fmaxf(fmaf(q1[0], scv[2], shv[2]), 0.f);                    \
            AL.w += fmaxf(fmaf(q1[1], scv[3], shv[3]), 0.f);                    \
            AH.x += fmaxf(fmaf(q2[0], scv[4], shv[4]), 0.f);                    \
            AH.y += fmaxf(fmaf(q2[1], scv[5], shv[5]), 0.f);                    \
            AH.z += fmaxf(fmaf(q3[0], scv[6], shv[6]), 0.f);                    \
            AH.w += fmaxf(fmaf(q3[1], scv[7], shv[7]), 0.f);                    \
        }
        int j = b;
        for (; j + 4 <= e; j += 4) {
            int s0 = eidx[j], s1 = eidx[j + 1], s2 = eidx[j + 2], s3 = eidx[j + 3];
            EDGE(s0, a0l, a0h) EDGE(s1, a1l, a1h) EDGE(s2, a2l, a2h) EDGE(s3, a3l, a3h)
        }
        for (; j < e; j++) {
            int s = eidx[j];
            EDGE(s, a0l, a0h)
        }
#undef EDGE
        float v0 = a0l.x + a1l.x + a2l.x + a3l.x;
        float v1 = a0l.y + a1l.y + a2l.y + a3l.y;
        float v2 = a0l.z + a1l.z + a2l.z + a3l.z;
        float v3 = a0l.w + a1l.w + a2l.w + a3l.w;
        float v4 = a0h.x + a1h.x + a2h.x + a3h.x;
        float v5 = a0h.y + a1h.y + a2h.y + a3h.y;
        float v6 = a0h.z + a1h.z + a2h.z + a3h.z;
        float v7 = a0h.w + a1h.w + a2h.w + a3h.w;
        float invd = 1.0f / fmaxf((float)(e - b), 1.0f);
        float4 o;
        ((__half2*)&o)[0] = __floats2half2_rn(v0 * invd, v1 * invd);
        ((__half2*)&o)[1] = __floats2half2_rn(v2 * invd, v3 * invd);
        ((__half2*)&o)[2] = __floats2half2_rn(v4 * invd, v5 * invd);
        ((__half2*)&o)[3] = __floats2half2_rn(v6 * invd, v7 * invd);
        *(float4*)(&sT[wv][(r * 8 + grp) * TSTRIDE + l8 * 8]) = o;
    }
    __syncthreads();    // drains LDS writes

    // ---- GEMM phase (unchanged) ----
    int m = lane & 15, quad = lane >> 4;
    if (node0 < n) {
        const f16x8* wf = (const f16x8*)wfh;   // frag idx ((q*4+tt)*4+quad)*16+m

        int nodeA = node0 + m;
        if (nodeA >= n) nodeA = n - 1;         // tail-safe global loads

        const uint2* hrow8 = (const uint2*)(hr_in + (size_t)nodeA * 16);
        uint2 rlo = hrow8[quad];               // channels quad*8 .. +7
        uint2 rhi = hrow8[4 + quad];           // channels 32+quad*8 .. +7
        f16x8 af[4];
        af[0] = *(const f16x8*)(&sT[wv][m * TSTRIDE + quad * 8]);
        af[1] = *(const f16x8*)(&sT[wv][m * TSTRIDE + 32 + quad * 8]);
        {
            int cb = quad * 8;
            f32x2 q0 = __builtin_amdgcn_cvt_pk_f32_fp8(rlo.x, false);
            f32x2 q1 = __builtin_amdgcn_cvt_pk_f32_fp8(rlo.x, true);
            f32x2 q2 = __builtin_amdgcn_cvt_pk_f32_fp8(rlo.y, false);
            f32x2 q3 = __builtin_amdgcn_cvt_pk_f32_fp8(rlo.y, true);
            f16x8 a2;
            a2[0] = (_Float16)fmaxf(fmaf(q0[0], ssc[cb+0], ssh[cb+0]), 0.f);
            a2[1] = (_Float16)fmaxf(fmaf(q0[1], ssc[cb+1], ssh[cb+1]), 0.f);
            a2[2] = (_Float16)fmaxf(fmaf(q1[0], ssc[cb+2], ssh[cb+2]), 0.f);
            a2[3] = (_Float16)fmaxf(fmaf(q1[1], ssc[cb+3], ssh[cb+3]), 0.f);
            a2[4] = (_Float16)fmaxf(fmaf(q2[0], ssc[cb+4], ssh[cb+4]), 0.f);
            a2[5] = (_Float16)fmaxf(fmaf(q2[1], ssc[cb+5], ssh[cb+5]), 0.f);
            a2[6] = (_Float16)fmaxf(fmaf(q3[0], ssc[cb+6], ssh[cb+6]), 0.f);
            a2[7] = (_Float16)fmaxf(fmaf(q3[1], ssc[cb+7], ssh[cb+7]), 0.f);
            af[2] = a2;
            int cb3 = 32 + quad * 8;
            q0 = __builtin_amdgcn_cvt_pk_f32_fp8(rhi.x, false);
            q1 = __builtin_amdgcn_cvt_pk_f32_fp8(rhi.x, true);
            q2 = __builtin_amdgcn_cvt_pk_f32_fp8(rhi.y, false);
            q3 = __builtin_amdgcn_cvt_pk_f32_fp8(rhi.y, true);
            f16x8 a3;
            a3[0] = (_Float16)fmaxf(fmaf(q0[0], ssc[cb3+0], ssh[cb3+0]), 0.f);
            a3[1] = (_Float16)fmaxf(fmaf(q0[1], ssc[cb3+1], ssh[cb3+1]), 0.f);
            a3[2] = (_Float16)fmaxf(fmaf(q1[0], ssc[cb3+2], ssh[cb3+2]), 0.f);
            a3[3] = (_Float16)fmaxf(fmaf(q1[1], ssc[cb3+3], ssh[cb3+3]), 0.f);
            a3[4] = (_Float16)fmaxf(fmaf(q2[0], ssc[cb3+4], ssh[cb3+4]), 0.f);
            a3[5] = (_Float16)fmaxf(fmaf(q2[1], ssc[cb3+5], ssh[cb3+5]), 0.f);
            a3[6] = (_Float16)fmaxf(fmaf(q3[0], ssc[cb3+6], ssh[cb3+6]), 0.f);
            a3[7] = (_Float16)fmaxf(fmaf(q3[1], ssc[cb3+7], ssh[cb3+7]), 0.f);
            af[3] = a3;
        }

#pragma unroll
        for (int tt = 0; tt < 4; tt++) {
            float bv = bias[tt * 16 + m];
            f32x4 c = {bv, bv, bv, bv};
#pragma unroll
            for (int q = 0; q < 4; q++)
                c = __builtin_amdgcn_mfma_f32_16x16x32_f16(
                        af[q], wf[((q * 4 + tt) * 4 + quad) * 16 + m], c, 0, 0, 0);
            float s = 0.f, ss = 0.f;
#pragma unroll
            for (int r = 0; r < 4; r++) {
                int row = node0 + quad * 4 + r;
                float v = (row < n) ? c[r] : 0.f;
                if (row < n) {
                    int pb = __builtin_amdgcn_cvt_pk_fp8_f32(v, v, 0, false);
                    hr_out[(size_t)row * 64 + tt * 16 + m] = (unsigned char)(pb & 0xFF);
                }
                s += v;
                ss = fmaf(v, v, ss);
            }
            s  += __shfl_xor(s, 16, 64);  s  += __shfl_xor(s, 32, 64);
            ss += __shfl_xor(ss, 16, 64); ss += __shfl_xor(ss, 32, 64);
            if (quad == 0) {
                atomicAdd(&ls[tt * 16 + m], s);
                atomicAdd(&lss[tt * 16 + m], ss);
            }
        }
    }
    __syncthreads();
    if (t < 64) {
        float* slot = statsTmp + (size_t)(blockIdx.x & 63) * 128;
        unsafeAtomicAdd(&slot[t], ls[t]);
        unsafeAtomicAdd(&slot[64 + t], lss[t]);
    }
}

// ---- stats_reduce: fold 64 scratch slots into stats[128] ------------------
__global__ __launch_bounds__(128) void stats_reduce(const float* __restrict__ tmp,
                                                    float* __restrict__ stats)
{
    int t = threadIdx.x;       // 0..127
    float s = 0.f;
#pragma unroll 8
    for (int k = 0; k < 64; k++) s += tmp[k * 128 + t];
    stats[t] = s;
}

// ---- fused layer-3 BN+ReLU + attention pooling (fp8 raw input) -----------
__global__ __launch_bounds__(256) void bn_pool(
    const unsigned* __restrict__ h8, const float* __restrict__ stats,
    const float* __restrict__ g, const float* __restrict__ be,
    const float* __restrict__ x, const int* __restrict__ batch,
    float* __restrict__ rawpool, float invN, int N, int chunk)
{
    int wid  = blockIdx.x * 4 + (threadIdx.x >> 6);
    int lane = threadIdx.x & 63;
    int i0 = wid * chunk;
    if (i0 >= N) return;
    int i1 = min(i0 + chunk, N);

    float mu  = stats[lane] * invN;
    float var = stats[64 + lane] * invN - mu * mu;
    float sc  = g[lane] / sqrtf(var + EPS_BN);
    float sh  = fmaf(-mu, sc, be[lane]);

    int dw = lane >> 2, s3 = lane & 3;
    int   cur = batch[i0];
    float acc = 0.f;
    for (int i = i0; i < i1; i++) {
        int bi = batch[i];
        if (bi != cur) {
            unsafeAtomicAdd(&rawpool[cur * 64 + lane], acc);
            acc = 0.f;
            cur = bi;
        }
        float w = expf(x[(size_t)i * 6 + 4]);
        unsigned d = h8[(size_t)i * 16 + dw];
        f32x2 lo = __builtin_amdgcn_cvt_pk_f32_fp8(d, false);
        f32x2 hi = __builtin_amdgcn_cvt_pk_f32_fp8(d, true);
        float hv = (s3 == 0) ? lo[0] : (s3 == 1) ? lo[1] : (s3 == 2) ? hi[0] : hi[1];
        float v = fmaxf(fmaf(hv, sc, sh), 0.f);
        acc = fmaf(v, w, acc);
    }
    unsafeAtomicAdd(&rawpool[cur * 64 + lane], acc);
}

// ---- heads: normalize rawpool by 1/sumexp and counts, then 2 tiny MLPs ----
__global__ __launch_bounds__(64) void heads_kernel(
    const float* __restrict__ rawpool, const float* __restrict__ sumexp,
    const int* __restrict__ lb,
    const float* __restrict__ phW1, const float* __restrict__ phb1,
    const float* __restrict__ phW2, const float* __restrict__ phb2,
    const float* __restrict__ trW1, const float* __restrict__ trb1,
    const float* __restrict__ trW2, const float* __restrict__ trb2,
    float* __restrict__ out)
{
    int b = blockIdx.x, t = threadIdx.x;
    __shared__ float p[64], h1[32], h2[16];
    float cnt = (float)(lb[b + 1] - lb[b]);
    p[t] = rawpool[b * 64 + t] / (sumexp[0] * fmaxf(cnt, 1.0f));
    __syncthreads();
    if (t < 32) {
        float s = phb1[t];
        for (int k = 0; k < 64; k++) s = fmaf(p[k], phW1[k * 32 + t], s);
        h1[t] = fmaxf(s, 0.f);
    } else if (t < 48) {
        int tt = t - 32;
        float s = trb1[tt];
        for (int k = 0; k < 64; k++) s = fmaf(p[k], trW1[k * 16 + tt], s);
        h2[tt] = fmaxf(s, 0.f);
    }
    __syncthreads();
    if (t < 3) {
        float s = phb2[t];
        for (int k = 0; k < 32; k++) s = fmaf(h1[k], phW2[k * 3 + t], s);
        out[b * 3 + t] = s;
    } else if (t == 63) {
        float s = trb2[0];
        for (int k = 0; k < 16; k++) s = fmaf(h2[k], trW2[k], s);
        out[192 + b] = 1.0f / (1.0f + expf(-s));
    }
}

extern "C" void kernel_launch(void* const* d_in, const int* in_sizes, int n_in,
                              void* d_out, int out_size, void* d_ws, size_t ws_size,
                              hipStream_t stream)
{
    const float* x     = (const float*)d_in[0];
    const int*   ei    = (const int*)d_in[1];
    const int*   batch = (const int*)d_in[2];
    const float* W1l = (const float*)d_in[3];
    const float* b1  = (const float*)d_in[4];
    const float* W1r = (const float*)d_in[5];
    const float* W2l = (const float*)d_in[6];
    const float* b2  = (const float*)d_in[7];
    const float* W2r = (const float*)d_in[8];
    const float* W3l = (const float*)d_in[9];
    const float* b3  = (const float*)d_in[10];
    const float* W3r = (const float*)d_in[11];
    const float* g1  = (const float*)d_in[12];
    const float* be1 = (const float*)d_in[13];
    const float* g2  = (const float*)d_in[14];
    const float* be2 = (const float*)d_in[15];
    const float* g3  = (const float*)d_in[16];
    const float* be3 = (const float*)d_in[17];
    const float* phW1 = (const float*)d_in[18];
    const float* phb1 = (const float*)d_in[19];
    const float* phW2 = (const float*)d_in[20];
    const float* phb2 = (const float*)d_in[21];
    const float* trW1 = (const float*)d_in[22];
    const float* trb1 = (const float*)d_in[23];
    const float* trW2 = (const float*)d_in[24];
    const float* trb2 = (const float*)d_in[25];

    const int N = in_sizes[0] / 6;
    const int E = in_sizes[1] / 2;
    const int* src = ei;
    const int* dst = ei + E;

    const int NB    = (N + 255) >> 8;          // 391 buckets
    const int nBlkA = (E + EPB - 1) / EPB;     // 196 partition blocks

    float* ws = (float*)d_ws;
    const size_t N16 = (size_t)N * 16;
    unsigned* hr1   = (unsigned*)ws;               // N*16 dwords (fp8 raw h1)
    unsigned* hr2   = hr1 + N16;                   // N*16 (fp8 raw h2)
    unsigned* hr3   = hr2 + N16;                   // N*16 (fp8 raw h3)
    int*   epck     = (int*)(hr3 + N16);           // E packed src|dl<<24
    int*   eidx     = epck + E;                    // E (CSR by dst)
    int*   blockBin = eidx + E;                    // nBlkA * NBIN
    // --- contiguous zero region: binTotal + stats + statsTmp(3x) + rawpool
    //     + sumexp
    int*   binTotal = blockBin + (size_t)nBlkA * NBIN;   // NBIN
    float* stats    = (float*)(binTotal + NBIN);   // 3 * 128
    float* statsTmp = stats + 384;                 // 3 * 64 * 128
    float* rawpool  = statsTmp + 24576;            // 64*64
    float* sumexp   = rawpool + 4096;              // 1 (pad 4)
    // --- end zero region ---
    int*   binBase  = (int*)(sumexp + 4);          // NBIN + 1
    int*   rowptr   = binBase + NBIN + 1;          // N + 1
    int*   lb       = rowptr + N + 1;              // 65 (pad 72)
    __half* wfrag2  = (__half*)(lb + 72);          // 8192 fp16
    __half* wfrag3  = wfrag2 + 8192;               // 8192 fp16
    float* out      = (float*)d_out;

    const int mfmaBlocks = (N + 63) / 64;          // 1563 (4 x 16-node tiles/block)
    const int PBLK = 1024;                         // bn_pool blocks (4 waves each)
    const int chunk = (N + PBLK * 4 - 1) / (PBLK * 4);
    const float invN = 1.0f / (float)N;

    // ---- zero accumulators; merged prep+hist ----
    size_t zbytes = (char*)(sumexp + 4) - (char*)binTotal;
    hipMemsetAsync(binTotal, 0, zbytes, stream);
    prep_hist<<<nBlkA + 321, 256, 0, stream>>>(dst, blockBin, binTotal, E, nBlkA,
                                               x, sumexp, N, batch, lb,
                                               W2l, W2r, W3l, W3r, wfrag2, wfrag3);

    // ---- CSR build ----
    blockbin_offs<<<NBIN / 8, 512, 0, stream>>>(blockBin, binTotal, binBase,
                                                rowptr + N, nBlkA);
    bucket_scatter<<<nBlkA, 256, 0, stream>>>(src, dst, blockBin, epck, E);

    // ---- merged CSR-local + layer 1 (raw fp8 h1 + transpose-read stats1) --
    csr_sage1<<<NB, 256, 0, stream>>>(epck, binBase, rowptr, eidx,
                                      x, W1l, b1, W1r, hr1,
                                      statsTmp + 16384, N);
    stats_reduce<<<1, 128, 0, stream>>>(statsTmp + 16384, stats);

    // ---- layer 2: BN1-on-the-fly gather+GEMM -> raw fp8 h2; stats2 slots --
    agg_mm_mfma<<<mfmaBlocks, 256, 0, stream>>>(rowptr, eidx, hr1,
                                                stats, g1, be1, wfrag2, b2,
                                                (unsigned char*)hr2, statsTmp,
                                                invN, N);
    stats_reduce<<<1, 128, 0, stream>>>(statsTmp, stats + 128);

    // ---- layer 3: BN2-on-the-fly gather+GEMM -> raw fp8 h3; stats3 slots --
    agg_mm_mfma<<<mfmaBlocks, 256, 0, stream>>>(rowptr, eidx, hr2,
                                                stats + 128, g2, be2, wfrag3, b3,
                                                (unsigned char*)hr3,
                                                statsTmp + 8192, invN, N);
    stats_reduce<<<1, 128, 0, stream>>>(statsTmp + 8192, stats + 256);

    // ---- fused BN3 + attention pooling + heads ----
    bn_pool<<<PBLK, 256, 0, stream>>>(hr3, stats + 256, g3, be3,
                                      x, batch, rawpool, invN, N, chunk);
    heads_kernel<<<64, 64, 0, stream>>>(rawpool, sumexp, lb,
                                        phW1, phb1, phW2, phb2,
                                        trW1, trb1, trW2, trb2, out);
}

// Round 13
// 297.016 us; speedup vs baseline: 1.0403x; 1.0403x over previous
//
#include <hip/hip_runtime.h>
#include <hip/hip_fp16.h>
#include <cstdint>
#include <cstddef>

// ---------------------------------------------------------------------------
// TopoGNN: 3x SAGEConv(mean) + BN + ReLU, softmax-attention pooling, 2 heads.
// N=100000 nodes, E=1600000 edges, B=64 segments, IN_CH=6, HID=64.
// R5 (754us) bucket-CSR. R12 (474us) MFMA GEMM. R17/R19 (381us) fp8 gather.
// R20 (373us) agg fused into MFMA. R21 (361us) merges. R22 (357us) h fp16.
// R23 (766us REGR): per-block __threadfence evicts L2. Never fence gathers.
// R24 (341us): fence-free merges. R25 (357us REGR): stats broadcast folds.
// R26 (339us): h16-elim. R27 (329us): BN-on-the-fly, raw h fp8.
// R28 (322.8us): stats1 in csr_sage1. R29 (300.8us): transpose-read stats1.
// R30 (325.1us REGR): deeper per-lane chains (8-wide in-lane unroll).
// R31 (299.9us): revert to R29. Anchor.
// R32 (309.0us REGR): 8x8 node-parallel gather — 2x VALU per chain link.
//     CLOSED: gather is issue-limited on the per-lane decode chain; the
//     4x16 geometry (1 dword, 4 slots) is the measured optimum. FETCH=53MB
//     (8 XCD x h8) is structural for random sources.
// R33: exact revert to R29/R31 anchor. Session: 363.7 -> ~300us.
// ---------------------------------------------------------------------------

#define EPB 8192   // edges per partition block (256 thr x 32)
#define NBIN 512   // padded bucket count (actual NB = ceil(N/256) <= 512)
#define EPS_BN 1e-5f

typedef _Float16 f16x8 __attribute__((ext_vector_type(8)));
typedef float    f32x4 __attribute__((ext_vector_type(4)));
typedef float    f32x2 __attribute__((ext_vector_type(2)));

// ---- merged: per-block bucket histogram (bid < nBlk) + prep roles --------
__global__ __launch_bounds__(256) void prep_hist(
    const int* __restrict__ dst, int* __restrict__ blockBin,
    int* __restrict__ binTotal, int E, int nBlk,
    const float* __restrict__ x, float* __restrict__ sumexp, int n,
    const int* __restrict__ batch, int* __restrict__ lb,
    const float* __restrict__ W2l, const float* __restrict__ W2r,
    const float* __restrict__ W3l, const float* __restrict__ W3r,
    __half* __restrict__ wfrag2, __half* __restrict__ wfrag3)
{
    __shared__ int hist[NBIN];
    __shared__ float wsum[4];
    int t = threadIdx.x;
    int bid = blockIdx.x;
    if (bid < nBlk) {
        for (int i = t; i < NBIN; i += 256) hist[i] = 0;
        __syncthreads();
        int e0 = bid * EPB;
#pragma unroll
        for (int k = 0; k < 32; k++) {
            int e = e0 + (k << 8) + t;
            if (e < E) atomicAdd(&hist[dst[e] >> 8], 1);
        }
        __syncthreads();
        for (int i = t; i < NBIN; i += 256) {
            int c = hist[i];
            blockBin[bid * NBIN + i] = c;
            if (c) atomicAdd(&binTotal[i], c);
        }
        return;
    }
    int pbid = bid - nBlk;
    if (pbid < 256) {
        float s = 0.f;
        int stride = 256 * 256;
        for (int i = pbid * 256 + t; i < n; i += stride)
            s += expf(x[(size_t)i * 6 + 4]);
#pragma unroll
        for (int o = 32; o > 0; o >>= 1) s += __shfl_down(s, o, 64);
        if ((t & 63) == 0) wsum[t >> 6] = s;
        __syncthreads();
        if (t == 0)
            unsafeAtomicAdd(sumexp, wsum[0] + wsum[1] + wsum[2] + wsum[3]);
    } else if (pbid == 256) {
        int b = t;
        if (b > 64) return;
        int lo = 0, hi = n;
        while (lo < hi) {
            int mid = (lo + hi) >> 1;
            if (batch[mid] < b) lo = mid + 1; else hi = mid;
        }
        lb[b] = lo;
    } else {
        bool second = (pbid >= 289);
        int i = (pbid - (second ? 289 : 257)) * 256 + t;
        if (i >= 8192) return;
        int j    = i & 7;
        int m    = (i >> 3) & 15;
        int quad = (i >> 7) & 3;
        int tt   = (i >> 9) & 3;
        int q    = i >> 11;
        int k    = (q & 1) * 32 + quad * 8 + j;
        int col  = tt * 16 + m;
        const float* W = second ? ((q < 2) ? W3l : W3r)
                                : ((q < 2) ? W2l : W2r);
        (second ? wfrag3 : wfrag2)[i] = __float2half_rn(W[k * 64 + col]);
    }
}

// ---- phase B: scan of bin totals + per-bin exclusive block-count scan ----
__global__ __launch_bounds__(512) void blockbin_offs(int* __restrict__ blockBin,
                                                     const int* __restrict__ binTotal,
                                                     int* __restrict__ binBase,
                                                     int* __restrict__ rowptrN,
                                                     int nBlk)
{
    __shared__ int s[NBIN];
    int t = threadIdx.x;
    int tot = binTotal[t];
    s[t] = tot;
    __syncthreads();
    for (int off = 1; off < NBIN; off <<= 1) {
        int v = (t >= off) ? s[t - off] : 0;
        __syncthreads();
        s[t] += v;
        __syncthreads();
    }
    int excl = s[t] - tot;
    if (blockIdx.x == 0) {
        binBase[t] = excl;
        if (t == NBIN - 1) { binBase[NBIN] = s[t]; *rowptrN = s[t]; }
    }
    __syncthreads();

    int wv   = t >> 6;              // 0..7
    int lane = t & 63;
    int bin  = blockIdx.x * 8 + wv;
    int carry = s[bin] - binTotal[bin];   // exclusive base for this bin
    for (int c0 = 0; c0 < nBlk; c0 += 64) {
        int blk = c0 + lane;
        int cnt = (blk < nBlk) ? blockBin[blk * NBIN + bin] : 0;
        int v = cnt;
#pragma unroll
        for (int d = 1; d < 64; d <<= 1) {
            int u = __shfl_up(v, d, 64);
            if (lane >= d) v += u;
        }
        if (blk < nBlk) blockBin[blk * NBIN + bin] = carry + v - cnt;
        carry += __shfl(v, 63, 64);
    }
}

// ---- phase C: place packed (src | local_dst<<24); per-block LDS cursors ---
__global__ __launch_bounds__(256) void bucket_scatter(const int* __restrict__ src,
                                                      const int* __restrict__ dst,
                                                      const int* __restrict__ blockBin,
                                                      int* __restrict__ epck, int E)
{
    __shared__ int cur[NBIN];
    int t = threadIdx.x;
    for (int i = t; i < NBIN; i += 256) cur[i] = blockBin[blockIdx.x * NBIN + i];
    __syncthreads();
    int e0 = blockIdx.x * EPB;
#pragma unroll
    for (int k = 0; k < 32; k++) {
        int e = e0 + (k << 8) + t;
        if (e < E) {
            int d = dst[e];
            int pos = atomicAdd(&cur[d >> 8], 1);
            epck[pos] = src[e] | ((d & 255) << 24);   // src < 2^24
        }
    }
}

// ---- merged phase D + layer 1 + layer-1 BN stats (transpose-read) --------
__global__ __launch_bounds__(256) void csr_sage1(
    const int* __restrict__ epck, const int* __restrict__ binBase,
    int* __restrict__ rowptr, int* __restrict__ eidx,
    const float* __restrict__ x,
    const float* __restrict__ Wl, const float* __restrict__ bias,
    const float* __restrict__ Wr, unsigned* __restrict__ out,
    float* __restrict__ statsTmp, int N)
{
    __shared__ int cnt[256], s[256], cur[256];
    __shared__ float4 sWl[6 * 16];
    __shared__ float4 sWr[6 * 16];
    __shared__ float ls[64], lss[64];
    __shared__ unsigned spx[256 * 16];   // 16KB: fp8 rows for stats transpose
    int t = threadIdx.x, bkt = blockIdx.x;
    for (int i = t; i < 6 * 16; i += 256) {
        sWl[i] = ((const float4*)Wl)[i];
        sWr[i] = ((const float4*)Wr)[i];
    }
    if (t < 64) { ls[t] = 0.f; lss[t] = 0.f; }
    int base = binBase[bkt], nE = binBase[bkt + 1] - base;
    cnt[t] = 0;
    __syncthreads();
    for (int j = t; j < nE; j += 256)
        atomicAdd(&cnt[(unsigned)epck[base + j] >> 24], 1);
    __syncthreads();
    s[t] = cnt[t];
    __syncthreads();
    for (int off = 1; off < 256; off <<= 1) {
        int v = (t >= off) ? s[t - off] : 0;
        __syncthreads();
        s[t] += v;
        __syncthreads();
    }
    int excl = s[t] - cnt[t];
    cur[t] = excl;
    int node = (bkt << 8) + t;
    bool valid = node < N;
    if (valid) rowptr[node] = base + excl;
    __syncthreads();
    for (int j = t; j < nE; j += 256) {
        int v = epck[base + j];
        int pos = atomicAdd(&cur[(unsigned)v >> 24], 1);
        eidx[base + pos] = v & 0xFFFFFF;     // contiguous 16KB span: stays in L2
    }
    __syncthreads();    // eidx writes drained to L2 before re-read; ls/lss init

    // ---- sage1 part: this block's nodes == this bucket (no early return) --
    int eb = base + excl, ee = base + s[t];   // empty for invalid nodes
    float a[6] = {0.f, 0.f, 0.f, 0.f, 0.f, 0.f};
    for (int j = eb; j < ee; j++) {
        int si = eidx[j];
        const float2* r = (const float2*)(x + (size_t)si * 6);
        float2 r0 = r[0], r1 = r[1], r2 = r[2];
        a[0] += r0.x; a[1] += r0.y; a[2] += r1.x;
        a[3] += r1.y; a[4] += r2.x; a[5] += r2.y;
    }
    float invd = 1.0f / fmaxf((float)(ee - eb), 1.0f);

    int nodeX = valid ? node : 0;             // OOB-safe x read
    const float2* xr2 = (const float2*)(x + (size_t)nodeX * 6);
    float2 x0 = xr2[0], x1 = xr2[1], x2 = xr2[2];
    float hh[6] = {x0.x, x0.y, x1.x, x1.y, x2.x, x2.y};

    float4 acc[16];
#pragma unroll
    for (int cg = 0; cg < 16; cg++) acc[cg] = ((const float4*)bias)[cg];
#pragma unroll
    for (int k = 0; k < 6; k++) {
        float am = a[k] * invd;
        float hk = hh[k];
#pragma unroll
        for (int cg = 0; cg < 16; cg++) {
            float4 wl = sWl[k * 16 + cg];
            float4 wr = sWr[k * 16 + cg];
            acc[cg].x = fmaf(am, wl.x, fmaf(hk, wr.x, acc[cg].x));
            acc[cg].y = fmaf(am, wl.y, fmaf(hk, wr.y, acc[cg].y));
            acc[cg].z = fmaf(am, wl.z, fmaf(hk, wr.z, acc[cg].z));
            acc[cg].w = fmaf(am, wl.w, fmaf(hk, wr.w, acc[cg].w));
        }
    }
    unsigned px[16];
#pragma unroll
    for (int cg = 0; cg < 16; cg++) {
        float4 av = acc[cg];
        int p = __builtin_amdgcn_cvt_pk_fp8_f32(av.x, av.y, 0, false);
        p     = __builtin_amdgcn_cvt_pk_fp8_f32(av.z, av.w, p, true);
        px[cg] = valid ? (unsigned)p : 0u;    // fp8 0x00 == +0.0 for stats
    }
    if (valid) {
        uint4* orow = (uint4*)(out + (size_t)node * 16);
        orow[0] = make_uint4(px[0],  px[1],  px[2],  px[3]);
        orow[1] = make_uint4(px[4],  px[5],  px[6],  px[7]);
        orow[2] = make_uint4(px[8],  px[9],  px[10], px[11]);
        orow[3] = make_uint4(px[12], px[13], px[14], px[15]);
    }
    // stage rows in LDS for the stats transpose
    {
        unsigned* row = &spx[t * 16];
#pragma unroll
        for (int cg = 0; cg < 16; cg++) row[cg] = px[cg];
    }
    __syncthreads();

    // ---- stats1 transpose-read: thread t = channel (t&63) x node-group ----
    {
        int c = t & 63, grp = t >> 6;
        int d = c >> 2, sh = (c & 3) * 8;
        float sv = 0.f, ssv = 0.f;
        const unsigned* col = &spx[(grp * 64) * 16 + d];
#pragma unroll 8
        for (int i = 0; i < 64; i++) {
            unsigned dw = col[i * 16];
            f32x2 p = __builtin_amdgcn_cvt_pk_f32_fp8(dw >> sh, false);
            float v = p[0];
            sv += v;
            ssv = fmaf(v, v, ssv);
        }
        atomicAdd(&ls[c], sv);
        atomicAdd(&lss[c], ssv);
    }
    __syncthreads();
    if (t < 64) {
        float* slot = statsTmp + (size_t)(bkt & 63) * 128;
        unsafeAtomicAdd(&slot[t], ls[t]);
        unsafeAtomicAdd(&slot[64 + t], lss[t]);
    }
}

// ---- fused BN-on-the-fly aggregation + MFMA GEMM + BN stats --------------
#define TSTRIDE 72
__global__ __launch_bounds__(256) void agg_mm_mfma(
    const int* __restrict__ rowptr, const int* __restrict__ eidx,
    const unsigned* __restrict__ hr_in,
    const float* __restrict__ stats, const float* __restrict__ g,
    const float* __restrict__ be,
    const __half* __restrict__ wfh, const float* __restrict__ bias,
    unsigned char* __restrict__ hr_out, float* __restrict__ statsTmp,
    float invN, int n)
{
    __shared__ float ls[64], lss[64];
    __shared__ float ssc[64], ssh[64];
    __shared__ _Float16 sT[4][16 * TSTRIDE];   // 4 waves x 16 nodes x 64ch
    int t = threadIdx.x;
    if (t < 64) {
        ls[t] = 0.f; lss[t] = 0.f;
        float mu  = stats[t] * invN;
        float var = stats[64 + t] * invN - mu * mu;
        float sc  = g[t] / sqrtf(var + EPS_BN);
        ssc[t] = sc;
        ssh[t] = fmaf(-mu, sc, be[t]);
    }
    __syncthreads();   // ssc/ssh visible to all waves

    int wv = t >> 6, lane = t & 63;
    int node0 = (blockIdx.x * 4 + wv) * 16;

    // ---- gather phase (BN+relu applied per decoded value) ----
    int grp = lane >> 4, cq = lane & 15;
    float sc0 = ssc[4 * cq],     sh0 = ssh[4 * cq];
    float sc1 = ssc[4 * cq + 1], sh1 = ssh[4 * cq + 1];
    float sc2 = ssc[4 * cq + 2], sh2 = ssh[4 * cq + 2];
    float sc3 = ssc[4 * cq + 3], sh3 = ssh[4 * cq + 3];
#pragma unroll 1
    for (int r = 0; r < 4; r++) {
        int node = node0 + r * 4 + grp;
        int b = 0, e = 0;
        if (node < n) { b = rowptr[node]; e = rowptr[node + 1]; }

        float4 a0 = {0,0,0,0}, a1 = {0,0,0,0}, a2 = {0,0,0,0}, a3 = {0,0,0,0};
#define EDGE(S, ACC)                                                            \
        {                                                                       \
            unsigned r_ = hr_in[(size_t)(S) * 16 + cq];                         \
            f32x2 lo_ = __builtin_amdgcn_cvt_pk_f32_fp8(r_, false);             \
            f32x2 hi_ = __builtin_amdgcn_cvt_pk_f32_fp8(r_, true);              \
            ACC.x += fmaxf(fmaf(lo_[0], sc0, sh0), 0.f);                        \
            ACC.y += fmaxf(fmaf(lo_[1], sc1, sh1), 0.f);                        \
            ACC.z += fmaxf(fmaf(hi_[0], sc2, sh2), 0.f);                        \
            ACC.w += fmaxf(fmaf(hi_[1], sc3, sh3), 0.f);                        \
        }
        int j = b;
        for (; j + 4 <= e; j += 4) {
            int s0 = eidx[j], s1 = eidx[j + 1], s2 = eidx[j + 2], s3 = eidx[j + 3];
            EDGE(s0, a0) EDGE(s1, a1) EDGE(s2, a2) EDGE(s3, a3)
        }
        for (; j < e; j++) {
            int s = eidx[j];
            EDGE(s, a0)
        }
#undef EDGE
        float ax = a0.x + a1.x + a2.x + a3.x;
        float ay = a0.y + a1.y + a2.y + a3.y;
        float az = a0.z + a1.z + a2.z + a3.z;
        float aw = a0.w + a1.w + a2.w + a3.w;
        float invd = 1.0f / fmaxf((float)(e - b), 1.0f);
        __half2 o01 = __floats2half2_rn(ax * invd, ay * invd);
        __half2 o23 = __floats2half2_rn(az * invd, aw * invd);
        float2 ov;
        ((__half2*)&ov)[0] = o01;
        ((__half2*)&ov)[1] = o23;
        *(float2*)(&sT[wv][(r * 4 + grp) * TSTRIDE + cq * 4]) = ov;
    }
    __syncthreads();    // drains LDS writes

    // ---- GEMM phase ----
    int m = lane & 15, quad = lane >> 4;
    if (node0 < n) {
        const f16x8* wf = (const f16x8*)wfh;   // frag idx ((q*4+tt)*4+quad)*16+m

        int nodeA = node0 + m;
        if (nodeA >= n) nodeA = n - 1;         // tail-safe global loads

        const uint2* hrow8 = (const uint2*)(hr_in + (size_t)nodeA * 16);
        uint2 rlo = hrow8[quad];               // channels quad*8 .. +7
        uint2 rhi = hrow8[4 + quad];           // channels 32+quad*8 .. +7
        f16x8 af[4];
        af[0] = *(const f16x8*)(&sT[wv][m * TSTRIDE + quad * 8]);
        af[1] = *(const f16x8*)(&sT[wv][m * TSTRIDE + 32 + quad * 8]);
        {
            int cb = quad * 8;
            f32x2 q0 = __builtin_amdgcn_cvt_pk_f32_fp8(rlo.x, false);
            f32x2 q1 = __builtin_amdgcn_cvt_pk_f32_fp8(rlo.x, true);
            f32x2 q2 = __builtin_amdgcn_cvt_pk_f32_fp8(rlo.y, false);
            f32x2 q3 = __builtin_amdgcn_cvt_pk_f32_fp8(rlo.y, true);
            f16x8 a2;
            a2[0] = (_Float16)fmaxf(fmaf(q0[0], ssc[cb+0], ssh[cb+0]), 0.f);
            a2[1] = (_Float16)fmaxf(fmaf(q0[1], ssc[cb+1], ssh[cb+1]), 0.f);
            a2[2] = (_Float16)fmaxf(fmaf(q1[0], ssc[cb+2], ssh[cb+2]), 0.f);
            a2[3] = (_Float16)fmaxf(fmaf(q1[1], ssc[cb+3], ssh[cb+3]), 0.f);
            a2[4] = (_Float16)fmaxf(fmaf(q2[0], ssc[cb+4], ssh[cb+4]), 0.f);
            a2[5] = (_Float16)fmaxf(fmaf(q2[1], ssc[cb+5], ssh[cb+5]), 0.f);
            a2[6] = (_Float16)fmaxf(fmaf(q3[0], ssc[cb+6], ssh[cb+6]), 0.f);
            a2[7] = (_Float16)fmaxf(fmaf(q3[1], ssc[cb+7], ssh[cb+7]), 0.f);
            af[2] = a2;
            int cb3 = 32 + quad * 8;
            q0 = __builtin_amdgcn_cvt_pk_f32_fp8(rhi.x, false);
            q1 = __builtin_amdgcn_cvt_pk_f32_fp8(rhi.x, true);
            q2 = __builtin_amdgcn_cvt_pk_f32_fp8(rhi.y, false);
            q3 = __builtin_amdgcn_cvt_pk_f32_fp8(rhi.y, true);
            f16x8 a3;
            a3[0] = (_Float16)fmaxf(fmaf(q0[0], ssc[cb3+0], ssh[cb3+0]), 0.f);
            a3[1] = (_Float16)fmaxf(fmaf(q0[1], ssc[cb3+1], ssh[cb3+1]), 0.f);
            a3[2] = (_Float16)fmaxf(fmaf(q1[0], ssc[cb3+2], ssh[cb3+2]), 0.f);
            a3[3] = (_Float16)fmaxf(fmaf(q1[1], ssc[cb3+3], ssh[cb3+3]), 0.f);
            a3[4] = (_Float16)fmaxf(fmaf(q2[0], ssc[cb3+4], ssh[cb3+4]), 0.f);
            a3[5] = (_Float16)fmaxf(fmaf(q2[1], ssc[cb3+5], ssh[cb3+5]), 0.f);
            a3[6] = (_Float16)fmaxf(fmaf(q3[0], ssc[cb3+6], ssh[cb3+6]), 0.f);
            a3[7] = (_Float16)fmaxf(fmaf(q3[1], ssc[cb3+7], ssh[cb3+7]), 0.f);
            af[3] = a3;
        }

#pragma unroll
        for (int tt = 0; tt < 4; tt++) {
            float bv = bias[tt * 16 + m];
            f32x4 c = {bv, bv, bv, bv};
#pragma unroll
            for (int q = 0; q < 4; q++)
                c = __builtin_amdgcn_mfma_f32_16x16x32_f16(
                        af[q], wf[((q * 4 + tt) * 4 + quad) * 16 + m], c, 0, 0, 0);
            float s = 0.f, ss = 0.f;
#pragma unroll
            for (int r = 0; r < 4; r++) {
                int row = node0 + quad * 4 + r;
                float v = (row < n) ? c[r] : 0.f;
                if (row < n) {
                    int pb = __builtin_amdgcn_cvt_pk_fp8_f32(v, v, 0, false);
                    hr_out[(size_t)row * 64 + tt * 16 + m] = (unsigned char)(pb & 0xFF);
                }
                s += v;
                ss = fmaf(v, v, ss);
            }
            s  += __shfl_xor(s, 16, 64);  s  += __shfl_xor(s, 32, 64);
            ss += __shfl_xor(ss, 16, 64); ss += __shfl_xor(ss, 32, 64);
            if (quad == 0) {
                atomicAdd(&ls[tt * 16 + m], s);
                atomicAdd(&lss[tt * 16 + m], ss);
            }
        }
    }
    __syncthreads();
    if (t < 64) {
        float* slot = statsTmp + (size_t)(blockIdx.x & 63) * 128;
        unsafeAtomicAdd(&slot[t], ls[t]);
        unsafeAtomicAdd(&slot[64 + t], lss[t]);
    }
}

// ---- stats_reduce: fold 64 scratch slots into stats[128] ------------------
__global__ __launch_bounds__(128) void stats_reduce(const float* __restrict__ tmp,
                                                    float* __restrict__ stats)
{
    int t = threadIdx.x;       // 0..127
    float s = 0.f;
#pragma unroll 8
    for (int k = 0; k < 64; k++) s += tmp[k * 128 + t];
    stats[t] = s;
}

// ---- fused layer-3 BN+ReLU + attention pooling (fp8 raw input) -----------
__global__ __launch_bounds__(256) void bn_pool(
    const unsigned* __restrict__ h8, const float* __restrict__ stats,
    const float* __restrict__ g, const float* __restrict__ be,
    const float* __restrict__ x, const int* __restrict__ batch,
    float* __restrict__ rawpool, float invN, int N, int chunk)
{
    int wid  = blockIdx.x * 4 + (threadIdx.x >> 6);
    int lane = threadIdx.x & 63;
    int i0 = wid * chunk;
    if (i0 >= N) return;
    int i1 = min(i0 + chunk, N);

    float mu  = stats[lane] * invN;
    float var = stats[64 + lane] * invN - mu * mu;
    float sc  = g[lane] / sqrtf(var + EPS_BN);
    float sh  = fmaf(-mu, sc, be[lane]);

    int dw = lane >> 2, s3 = lane & 3;
    int   cur = batch[i0];
    float acc = 0.f;
    for (int i = i0; i < i1; i++) {
        int bi = batch[i];
        if (bi != cur) {
            unsafeAtomicAdd(&rawpool[cur * 64 + lane], acc);
            acc = 0.f;
            cur = bi;
        }
        float w = expf(x[(size_t)i * 6 + 4]);
        unsigned d = h8[(size_t)i * 16 + dw];
        f32x2 lo = __builtin_amdgcn_cvt_pk_f32_fp8(d, false);
        f32x2 hi = __builtin_amdgcn_cvt_pk_f32_fp8(d, true);
        float hv = (s3 == 0) ? lo[0] : (s3 == 1) ? lo[1] : (s3 == 2) ? hi[0] : hi[1];
        float v = fmaxf(fmaf(hv, sc, sh), 0.f);
        acc = fmaf(v, w, acc);
    }
    unsafeAtomicAdd(&rawpool[cur * 64 + lane], acc);
}

// ---- heads: normalize rawpool by 1/sumexp and counts, then 2 tiny MLPs ----
__global__ __launch_bounds__(64) void heads_kernel(
    const float* __restrict__ rawpool, const float* __restrict__ sumexp,
    const int* __restrict__ lb,
    const float* __restrict__ phW1, const float* __restrict__ phb1,
    const float* __restrict__ phW2, const float* __restrict__ phb2,
    const float* __restrict__ trW1, const float* __restrict__ trb1,
    const float* __restrict__ trW2, const float* __restrict__ trb2,
    float* __restrict__ out)
{
    int b = blockIdx.x, t = threadIdx.x;
    __shared__ float p[64], h1[32], h2[16];
    float cnt = (float)(lb[b + 1] - lb[b]);
    p[t] = rawpool[b * 64 + t] / (sumexp[0] * fmaxf(cnt, 1.0f));
    __syncthreads();
    if (t < 32) {
        float s = phb1[t];
        for (int k = 0; k < 64; k++) s = fmaf(p[k], phW1[k * 32 + t], s);
        h1[t] = fmaxf(s, 0.f);
    } else if (t < 48) {
        int tt = t - 32;
        float s = trb1[tt];
        for (int k = 0; k < 64; k++) s = fmaf(p[k], trW1[k * 16 + tt], s);
        h2[tt] = fmaxf(s, 0.f);
    }
    __syncthreads();
    if (t < 3) {
        float s = phb2[t];
        for (int k = 0; k < 32; k++) s = fmaf(h1[k], phW2[k * 3 + t], s);
        out[b * 3 + t] = s;
    } else if (t == 63) {
        float s = trb2[0];
        for (int k = 0; k < 16; k++) s = fmaf(h2[k], trW2[k], s);
        out[192 + b] = 1.0f / (1.0f + expf(-s));
    }
}

extern "C" void kernel_launch(void* const* d_in, const int* in_sizes, int n_in,
                              void* d_out, int out_size, void* d_ws, size_t ws_size,
                              hipStream_t stream)
{
    const float* x     = (const float*)d_in[0];
    const int*   ei    = (const int*)d_in[1];
    const int*   batch = (const int*)d_in[2];
    const float* W1l = (const float*)d_in[3];
    const float* b1  = (const float*)d_in[4];
    const float* W1r = (const float*)d_in[5];
    const float* W2l = (const float*)d_in[6];
    const float* b2  = (const float*)d_in[7];
    const float* W2r = (const float*)d_in[8];
    const float* W3l = (const float*)d_in[9];
    const float* b3  = (const float*)d_in[10];
    const float* W3r = (const float*)d_in[11];
    const float* g1  = (const float*)d_in[12];
    const float* be1 = (const float*)d_in[13];
    const float* g2  = (const float*)d_in[14];
    const float* be2 = (const float*)d_in[15];
    const float* g3  = (const float*)d_in[16];
    const float* be3 = (const float*)d_in[17];
    const float* phW1 = (const float*)d_in[18];
    const float* phb1 = (const float*)d_in[19];
    const float* phW2 = (const float*)d_in[20];
    const float* phb2 = (const float*)d_in[21];
    const float* trW1 = (const float*)d_in[22];
    const float* trb1 = (const float*)d_in[23];
    const float* trW2 = (const float*)d_in[24];
    const float* trb2 = (const float*)d_in[25];

    const int N = in_sizes[0] / 6;
    const int E = in_sizes[1] / 2;
    const int* src = ei;
    const int* dst = ei + E;

    const int NB    = (N + 255) >> 8;          // 391 buckets
    const int nBlkA = (E + EPB - 1) / EPB;     // 196 partition blocks

    float* ws = (float*)d_ws;
    const size_t N16 = (size_t)N * 16;
    unsigned* hr1   = (unsigned*)ws;               // N*16 dwords (fp8 raw h1)
    unsigned* hr2   = hr1 + N16;                   // N*16 (fp8 raw h2)
    unsigned* hr3   = hr2 + N16;                   // N*16 (fp8 raw h3)
    int*   epck     = (int*)(hr3 + N16);           // E packed src|dl<<24
    int*   eidx     = epck + E;                    // E (CSR by dst)
    int*   blockBin = eidx + E;                    // nBlkA * NBIN
    // --- contiguous zero region: binTotal + stats + statsTmp(3x) + rawpool
    //     + sumexp
    int*   binTotal = blockBin + (size_t)nBlkA * NBIN;   // NBIN
    float* stats    = (float*)(binTotal + NBIN);   // 3 * 128
    float* statsTmp = stats + 384;                 // 3 * 64 * 128
    float* rawpool  = statsTmp + 24576;            // 64*64
    float* sumexp   = rawpool + 4096;              // 1 (pad 4)
    // --- end zero region ---
    int*   binBase  = (int*)(sumexp + 4);          // NBIN + 1
    int*   rowptr   = binBase + NBIN + 1;          // N + 1
    int*   lb       = rowptr + N + 1;              // 65 (pad 72)
    __half* wfrag2  = (__half*)(lb + 72);          // 8192 fp16
    __half* wfrag3  = wfrag2 + 8192;               // 8192 fp16
    float* out      = (float*)d_out;

    const int mfmaBlocks = (N + 63) / 64;          // 1563 (4 x 16-node tiles/block)
    const int PBLK = 1024;                         // bn_pool blocks (4 waves each)
    const int chunk = (N + PBLK * 4 - 1) / (PBLK * 4);
    const float invN = 1.0f / (float)N;

    // ---- zero accumulators; merged prep+hist ----
    size_t zbytes = (char*)(sumexp + 4) - (char*)binTotal;
    hipMemsetAsync(binTotal, 0, zbytes, stream);
    prep_hist<<<nBlkA + 321, 256, 0, stream>>>(dst, blockBin, binTotal, E, nBlkA,
                                               x, sumexp, N, batch, lb,
                                               W2l, W2r, W3l, W3r, wfrag2, wfrag3);

    // ---- CSR build ----
    blockbin_offs<<<NBIN / 8, 512, 0, stream>>>(blockBin, binTotal, binBase,
                                                rowptr + N, nBlkA);
    bucket_scatter<<<nBlkA, 256, 0, stream>>>(src, dst, blockBin, epck, E);

    // ---- merged CSR-local + layer 1 (raw fp8 h1 + transpose-read stats1) --
    csr_sage1<<<NB, 256, 0, stream>>>(epck, binBase, rowptr, eidx,
                                      x, W1l, b1, W1r, hr1,
                                      statsTmp + 16384, N);
    stats_reduce<<<1, 128, 0, stream>>>(statsTmp + 16384, stats);

    // ---- layer 2: BN1-on-the-fly gather+GEMM -> raw fp8 h2; stats2 slots --
    agg_mm_mfma<<<mfmaBlocks, 256, 0, stream>>>(rowptr, eidx, hr1,
                                                stats, g1, be1, wfrag2, b2,
                                                (unsigned char*)hr2, statsTmp,
                                                invN, N);
    stats_reduce<<<1, 128, 0, stream>>>(statsTmp, stats + 128);

    // ---- layer 3: BN2-on-the-fly gather+GEMM -> raw fp8 h3; stats3 slots --
    agg_mm_mfma<<<mfmaBlocks, 256, 0, stream>>>(rowptr, eidx, hr2,
                                                stats + 128, g2, be2, wfrag3, b3,
                                                (unsigned char*)hr3,
                                                statsTmp + 8192, invN, N);
    stats_reduce<<<1, 128, 0, stream>>>(statsTmp + 8192, stats + 256);

    // ---- fused BN3 + attention pooling + heads ----
    bn_pool<<<PBLK, 256, 0, stream>>>(hr3, stats + 256, g3, be3,
                                      x, batch, rawpool, invN, N, chunk);
    heads_kernel<<<64, 64, 0, stream>>>(rawpool, sumexp, lb,
                                        phW1, phb1, phW2, phb2,
                                        trW1, trb1, trW2, trb2, out);
}